// Round 1
// baseline (602.290 us; speedup 1.0000x reference)
//
#include <hip/hip_runtime.h>
#include <hip/hip_bf16.h>

// ---------------------------------------------------------------------------
// Transformer block (B=8, N=1024, D=1024, H=16, HD=64, FF=4096), fp32 in/out.
// bf16 MFMA GEMMs, flash attention, fused epilogues.
// R6: QKV + fc1 moved to a 256x256 / BK=64 / 8-wave / 4-phase-per-K-tile
// kernel with counted vmcnt (never 0 in steady state), raw s_barrier,
// setprio around MFMA clusters (T2+T3+T4+T5). proj/fc2 remain on the 128^2
// 2-phase kernel (N=1024 gives only 128 blocks at 256^2 -> half CUs idle).
// ---------------------------------------------------------------------------

typedef __attribute__((ext_vector_type(8))) short short8;
typedef __attribute__((ext_vector_type(4))) float floatx4;

__device__ __forceinline__ unsigned short f2bf(float f) {
  union { __hip_bfloat16 h; unsigned short u; } cv;
  cv.h = __float2bfloat16(f);
  return cv.u;
}

// 2^x via the native v_exp_f32 instruction (avoid glibc __exp2f macro clash)
__device__ __forceinline__ float fast_exp2(float x) {
  return __builtin_amdgcn_exp2f(x);
}

__device__ __forceinline__ void async_ld16(const void* g, void* l) {
  __builtin_amdgcn_global_load_lds(
      (const __attribute__((address_space(1))) unsigned int*)g,
      (__attribute__((address_space(3))) unsigned int*)l, 16, 0, 0);
}

#define VMCNT(n) asm volatile("s_waitcnt vmcnt(" #n ")" ::: "memory")

// ---------------- fp32 -> bf16 weight conversion (4 elems/thread) ----------
__global__ __launch_bounds__(256) void cvt_bf16(const float* __restrict__ in,
                                                unsigned short* __restrict__ out) {
  const long i = ((long)blockIdx.x * 256 + threadIdx.x) * 4;
  const float4 v = *(const float4*)(in + i);
  ushort4 o;
  o.x = f2bf(v.x); o.y = f2bf(v.y); o.z = f2bf(v.z); o.w = f2bf(v.w);
  *(ushort4*)(out + i) = o;
}

// ---------------- LayerNorm: fp32 row -> bf16 row (one block per row) ------
__global__ __launch_bounds__(256) void ln_bf16(const float* __restrict__ x,
                                               const float* __restrict__ g,
                                               const float* __restrict__ b,
                                               unsigned short* __restrict__ out) {
  const int row = blockIdx.x;
  const int tid = threadIdx.x;
  const float4 v = ((const float4*)(x + (long)row * 1024))[tid];
  float s = v.x + v.y + v.z + v.w;
  float ss = v.x * v.x + v.y * v.y + v.z * v.z + v.w * v.w;
#pragma unroll
  for (int off = 1; off < 64; off <<= 1) {
    s += __shfl_xor(s, off);
    ss += __shfl_xor(ss, off);
  }
  __shared__ float red[8];
  const int wave = tid >> 6, lane = tid & 63;
  if (lane == 0) { red[wave] = s; red[4 + wave] = ss; }
  __syncthreads();
  if (tid == 0) {
    red[0] = red[0] + red[1] + red[2] + red[3];
    red[4] = red[4] + red[5] + red[6] + red[7];
  }
  __syncthreads();
  const float mu = red[0] * (1.f / 1024.f);
  const float var = red[4] * (1.f / 1024.f) - mu * mu;
  const float rstd = rsqrtf(var + 1e-5f);
  const int c = tid * 4;
  ushort4 o;
  o.x = f2bf((v.x - mu) * rstd * g[c + 0] + b[c + 0]);
  o.y = f2bf((v.y - mu) * rstd * g[c + 1] + b[c + 1]);
  o.z = f2bf((v.z - mu) * rstd * g[c + 2] + b[c + 2]);
  o.w = f2bf((v.w - mu) * rstd * g[c + 3] + b[c + 3]);
  ((ushort4*)(out + (long)row * 1024))[tid] = o;
}

// ---------------- 128^2 GEMM (2-phase, kept for proj / fc2, N=1024) --------
#define BM 128
#define BN 128
#define BK 32

template <int MODE>
__global__ __launch_bounds__(256) void gemm_bt(
    const unsigned short* __restrict__ A, const unsigned short* __restrict__ B,
    int M, int N, int Kd,
    const float* __restrict__ b0, const float* __restrict__ b1,
    const float* __restrict__ resid,
    void* __restrict__ out0, void* __restrict__ out1, void* __restrict__ out2) {
  __shared__ unsigned short lA[2][BM * BK];
  __shared__ unsigned short lB[2][BN * BK];
  const int tid = threadIdx.x;
  const int wave = tid >> 6, lane = tid & 63;
  const int l16 = lane & 15, quad = lane >> 4;
  const int wr = wave >> 1, wc = wave & 1;
  const int bid = blockIdx.x;
  const int xcd = bid & 7;
  const int s = bid >> 3;
  const long m0 = (long)(xcd * 8 + (s & 7)) * BM;
  const long n0 = (long)(s >> 3) * BN;

  const int row = tid >> 2;
  const int kc = (tid & 3) ^ ((row >> 1) & 3);
  const unsigned short* aSrc = A + (m0 + row) * Kd + kc * 8;
  const unsigned short* bSrc = B + (n0 + row) * Kd + kc * 8;
  const int ldsOff0 = wave * 1024;
  const int ldsOff1 = wave * 1024 + 4096;

  floatx4 acc[4][4];
#pragma unroll
  for (int i = 0; i < 4; i++)
#pragma unroll
    for (int j = 0; j < 4; j++) acc[i][j] = (floatx4){0.f, 0.f, 0.f, 0.f};

  async_ld16(aSrc, (char*)&lA[0][0] + ldsOff0);
  async_ld16(aSrc + 64 * Kd, (char*)&lA[0][0] + ldsOff1);
  async_ld16(bSrc, (char*)&lB[0][0] + ldsOff0);
  async_ld16(bSrc + 64 * Kd, (char*)&lB[0][0] + ldsOff1);

  const int sw = ((l16 >> 1) & 3);

  for (int k0 = 0; k0 < Kd; k0 += BK) {
    const int buf = (k0 >> 5) & 1;
    __syncthreads();
    const int kn = k0 + BK;
    if (kn < Kd) {
      async_ld16(aSrc + kn, (char*)&lA[buf ^ 1][0] + ldsOff0);
      async_ld16(aSrc + 64 * Kd + kn, (char*)&lA[buf ^ 1][0] + ldsOff1);
      async_ld16(bSrc + kn, (char*)&lB[buf ^ 1][0] + ldsOff0);
      async_ld16(bSrc + 64 * Kd + kn, (char*)&lB[buf ^ 1][0] + ldsOff1);
    }
    short8 af[4], bfv[4];
#pragma unroll
    for (int mi = 0; mi < 4; mi++) {
      const int r = wr * 64 + mi * 16 + l16;
      af[mi] = *(const short8*)(&lA[buf][(r * 4 + (quad ^ sw)) * 8]);
    }
#pragma unroll
    for (int ni = 0; ni < 4; ni++) {
      const int r = wc * 64 + ni * 16 + l16;
      bfv[ni] = *(const short8*)(&lB[buf][(r * 4 + (quad ^ sw)) * 8]);
    }
#pragma unroll
    for (int mi = 0; mi < 4; mi++)
#pragma unroll
      for (int ni = 0; ni < 4; ni++)
        acc[mi][ni] = __builtin_amdgcn_mfma_f32_16x16x32_bf16(
            af[mi], bfv[ni], acc[mi][ni], 0, 0, 0);
  }

#pragma unroll
  for (int mi = 0; mi < 4; mi++) {
    const long rbase = m0 + wr * 64 + mi * 16 + quad * 4;
#pragma unroll
    for (int ni = 0; ni < 4; ni++) {
      const long cg = n0 + wc * 64 + ni * 16 + l16;
#pragma unroll
      for (int reg = 0; reg < 4; reg++) {
        const long rr = rbase + reg;
        const float val = acc[mi][ni][reg];
        if (MODE == 0) {
          const int which = (int)(cg >> 10);
          const int col = (int)(cg & 1023);
          const int bidx = (int)(rr >> 10), t = (int)(rr & 1023);
          const int head = col >> 6, hd = col & 63;
          const long bh = bidx * 16 + head;
          if (which == 0) {
            ((unsigned short*)out0)[(bh * 1024 + t) * 64 + hd] =
                f2bf((val + b0[col]) * 0.1803368801111244f);
          } else if (which == 1) {
            ((unsigned short*)out1)[(bh * 1024 + t) * 64 + hd] = f2bf(val);
          } else {
            ((unsigned short*)out2)[(bh * 64 + hd) * 1024 + t] =
                f2bf(val + b1[col]);
          }
        } else if (MODE == 1) {
          const long idx = rr * N + cg;
          ((float*)out0)[idx] = resid[idx] + val + b0[cg];
        } else {
          const float u = val + b0[cg];
          const float gl = 0.5f * u * (1.0f + erff(u * 0.70710678118f));
          ((unsigned short*)out0)[rr * N + cg] = f2bf(gl);
        }
      }
    }
  }
}

// ---------------- 256^2 GEMM, 8-wave, BK=64, 4-phase counted-vmcnt ---------
// Grid: (M/256 must be 32). bid -> xcd=bid&7, s=bid>>3, mt=xcd*4+(s&3),
// nt=s>>2. LDS = 2 buf x 8 chunks x 8KB = 128 KiB (chunks 0-3 = A 64-row
// quarters, 4-7 = B 64-row quarters). Granule swizzle: slot = g ^ (row&7)
// at 128B row stride -> every ds_read_b128 hits all 8 bank-groups with 8
// lanes each (balanced, conflict-free). global_load_lds stages linearly
// (granule index = tid); swizzle folded into the GLOBAL source column.
//
// Phase order per K-tile u (hm,hn): (0,0) (0,1) (1,1) (1,0). Staging:
//   ph1: B45(u+1)->nxt   ph2: B67(u+1)->nxt  [W_m: vmcnt(4)]
//   ph3: A02(u+2)->cur (slots freed at ph2)  ph4: A13(u+1)->nxt
//   [W_b: vmcnt(4)]
// FIFO invariant entering K-tile u: outstanding = [A02(u+1), A13(u)] (4).
// W_m forces those 4 (A13(u) needed at ph3); W_b forces B(u+1) (needed at
// u+1 ph1), leaving [A02(u+2), A13(u+1)]. Tails: W_m -> vmcnt(0) when no
// B(u+1) staged; W_b -> vmcnt(2) when no A02(u+2); skipped on last tile.
// Requires NT >= 2 (all call sites have NT=16).
template <int MODE>
__global__ __launch_bounds__(512, 2) void gemm8(
    const unsigned short* __restrict__ A, const unsigned short* __restrict__ B,
    int M, int N, int Kd,
    const float* __restrict__ b0, const float* __restrict__ b1,
    const float* __restrict__ resid,
    void* __restrict__ out0, void* __restrict__ out1, void* __restrict__ out2) {
  __shared__ __align__(16) unsigned short lds[2][8][4096];
  const int tid = threadIdx.x;
  const int wave = tid >> 6, lane = tid & 63;
  const int l16 = lane & 15, quad = lane >> 4;
  const int q7 = l16 & 7;
  const int wr = wave >> 2, wc = wave & 3;  // 2x4 wave grid, wave = 128x64 out
  const int bid = blockIdx.x;
  const int xcd = bid & 7, s = bid >> 3;
  const long m0 = (long)(xcd * 4 + (s & 3)) * 256;
  const long n0 = (long)(s >> 2) * 256;
  const int NT = Kd >> 6;

  // staging source (granule-swizzled on the global side; LDS side linear)
  const int srow = tid >> 3;
  const int sg = (tid & 7) ^ (srow & 7);
  const unsigned short* aS = A + (m0 + srow) * Kd + sg * 8;
  const unsigned short* bS = B + (n0 + srow) * Kd + sg * 8;
  const int wvOff = wave * 1024;

#define STAGE_A(c, kk, bp) \
  async_ld16(aS + (long)(c) * 64 * Kd + (kk), (char*)&lds[bp][c][0] + wvOff)
#define STAGE_B(c, kk, bp) \
  async_ld16(bS + (long)(c) * 64 * Kd + (kk), (char*)&lds[bp][4 + (c)][0] + wvOff)

  floatx4 acc[8][4];
#pragma unroll
  for (int i = 0; i < 8; i++)
#pragma unroll
    for (int j = 0; j < 4; j++) acc[i][j] = (floatx4){0.f, 0.f, 0.f, 0.f};

  short8 af[4][2];  // current hm half: 4 M-frags x 2 k-slices
  short8 bf[4][2];  // all 4 N-frags x 2 k-slices (held across the K-tile)

#define RD_A(CP)                                                     \
  _Pragma("unroll") for (int mi = 0; mi < 4; mi++) {                 \
    const char* p_ = (CP) + (mi * 16 + l16) * 128;                   \
    af[mi][0] = *(const short8*)(p_ + ((quad ^ q7) * 16));           \
    af[mi][1] = *(const short8*)(p_ + (((4 + quad) ^ q7) * 16));     \
  }
#define RD_B(HN)                                                         \
  _Pragma("unroll") for (int ni = 0; ni < 2; ni++) {                     \
    const char* p_ = bC + (((HN)*32) + ni * 16 + l16) * 128;             \
    bf[(HN)*2 + ni][0] = *(const short8*)(p_ + ((quad ^ q7) * 16));      \
    bf[(HN)*2 + ni][1] = *(const short8*)(p_ + (((4 + quad) ^ q7) * 16)); \
  }
#define MFMA_PHASE(HM, HN)                                                   \
  __builtin_amdgcn_s_setprio(1);                                             \
  _Pragma("unroll") for (int mi = 0; mi < 4; mi++) {                         \
    _Pragma("unroll") for (int ni = 0; ni < 2; ni++) {                       \
      floatx4 c_ = acc[(HM)*4 + mi][(HN)*2 + ni];                            \
      c_ = __builtin_amdgcn_mfma_f32_16x16x32_bf16(af[mi][0],                \
                                                   bf[(HN)*2 + ni][0], c_,   \
                                                   0, 0, 0);                 \
      c_ = __builtin_amdgcn_mfma_f32_16x16x32_bf16(af[mi][1],                \
                                                   bf[(HN)*2 + ni][1], c_,   \
                                                   0, 0, 0);                 \
      acc[(HM)*4 + mi][(HN)*2 + ni] = c_;                                    \
    }                                                                        \
  }                                                                          \
  __builtin_amdgcn_s_setprio(0);

  // prologue (FIFO order matches steady-state invariant)
  STAGE_A(0, 0, 0); STAGE_A(2, 0, 0);
  STAGE_B(0, 0, 0); STAGE_B(1, 0, 0); STAGE_B(2, 0, 0); STAGE_B(3, 0, 0);
  STAGE_A(0, 64, 1); STAGE_A(2, 64, 1);  // A02(1)  (NT >= 2)
  STAGE_A(1, 0, 0); STAGE_A(3, 0, 0);    // A13(0)
  VMCNT(4);  // forces A02(0)+B(0); leaves [A02(1), A13(0)]
  __builtin_amdgcn_s_barrier();

  for (int u = 0; u < NT; ++u) {
    const int buf = u & 1, nxt = buf ^ 1;
    const long kk1 = (long)(u + 1) << 6;
    const long kk2 = (long)(u + 2) << 6;
    const char* aC0 = (const char*)&lds[buf][wr * 2][0];
    const char* aC1 = (const char*)&lds[buf][wr * 2 + 1][0];
    const char* bC = (const char*)&lds[buf][4 + wc][0];

    // ---- ph1 (hm0, hn0)
    RD_A(aC0);
    RD_B(0);
    if (u + 1 < NT) { STAGE_B(0, kk1, nxt); STAGE_B(1, kk1, nxt); }
    __builtin_amdgcn_s_barrier();
    MFMA_PHASE(0, 0);
    __builtin_amdgcn_s_barrier();

    // ---- ph2 (hm0, hn1)
    RD_B(1);
    if (u + 1 < NT) { STAGE_B(2, kk1, nxt); STAGE_B(3, kk1, nxt); }
    __builtin_amdgcn_s_barrier();
    MFMA_PHASE(0, 1);
    if (u + 1 < NT) { VMCNT(4); } else { VMCNT(0); }  // W_m: A13(u) landed
    __builtin_amdgcn_s_barrier();

    // ---- ph3 (hm1, hn1) -- A02(u+2) into freed slots of current buffer
    RD_A(aC1);
    if (u + 2 < NT) { STAGE_A(0, kk2, buf); STAGE_A(2, kk2, buf); }
    __builtin_amdgcn_s_barrier();
    MFMA_PHASE(1, 1);
    __builtin_amdgcn_s_barrier();

    // ---- ph4 (hm1, hn0) -- reuses bf[0..1] from ph1
    if (u + 1 < NT) { STAGE_A(1, kk1, nxt); STAGE_A(3, kk1, nxt); }
    __builtin_amdgcn_s_barrier();
    MFMA_PHASE(1, 0);
    if (u < NT - 1) {
      if (u + 2 < NT) { VMCNT(4); } else { VMCNT(2); }  // W_b: B(u+1) landed
      __builtin_amdgcn_s_barrier();
    }
  }

  // epilogue
#pragma unroll
  for (int mi2 = 0; mi2 < 8; mi2++) {
    const long rbase = m0 + wr * 128 + mi2 * 16 + quad * 4;
#pragma unroll
    for (int nj = 0; nj < 4; nj++) {
      const long cg = n0 + wc * 64 + nj * 16 + l16;
#pragma unroll
      for (int reg = 0; reg < 4; reg++) {
        const long rr = rbase + reg;
        const float val = acc[mi2][nj][reg];
        if (MODE == 0) {
          const int which = (int)(cg >> 10);
          const int col = (int)(cg & 1023);
          const int bidx = (int)(rr >> 10), t = (int)(rr & 1023);
          const int head = col >> 6, hd = col & 63;
          const long bh = bidx * 16 + head;
          if (which == 0) {
            ((unsigned short*)out0)[(bh * 1024 + t) * 64 + hd] =
                f2bf((val + b0[col]) * 0.1803368801111244f);
          } else if (which == 1) {
            ((unsigned short*)out1)[(bh * 1024 + t) * 64 + hd] = f2bf(val);
          } else {
            ((unsigned short*)out2)[(bh * 64 + hd) * 1024 + t] =
                f2bf(val + b1[col]);
          }
        } else if (MODE == 1) {
          const long idx = rr * N + cg;
          ((float*)out0)[idx] = resid[idx] + val + b0[cg];
        } else {
          const float u2 = val + b0[cg];
          const float gl = 0.5f * u2 * (1.0f + erff(u2 * 0.70710678118f));
          ((unsigned short*)out0)[rr * N + cg] = f2bf(gl);
        }
      }
    }
  }
  (void)M;
#undef STAGE_A
#undef STAGE_B
#undef RD_A
#undef RD_B
#undef MFMA_PHASE
}

// ---------------- Flash attention, LDS-shared K/V --------------------------
__global__ __launch_bounds__(256) void attn(const unsigned short* __restrict__ Q,
                                            const unsigned short* __restrict__ Kc,
                                            const unsigned short* __restrict__ Vt,
                                            unsigned short* __restrict__ O) {
  __shared__ unsigned short lK[2][2048];
  __shared__ unsigned short lV[2][2048];
  __shared__ float P[4][2][16][34];
  const int tid = threadIdx.x;
  const int wave = tid >> 6, lane = tid & 63;
  const int l16 = lane & 15, quad = lane >> 4;
  const int bid = blockIdx.x;
  const int xcd = bid & 7;
  const int sl = bid >> 3;
  const int bh = xcd * 16 + (sl & 15);
  const int q0 = (sl >> 4) * 128 + wave * 32;
  const unsigned short* Qb = Q + ((long)bh * 1024 + q0) * 64;
  const unsigned short* Kb = Kc + (long)bh * 65536;
  const unsigned short* Vb = Vt + (long)bh * 65536;

  short8 qf[2][2];
#pragma unroll
  for (int t = 0; t < 2; t++)
#pragma unroll
    for (int h = 0; h < 2; h++)
      qf[t][h] = *(const short8*)(Qb + (t * 16 + l16) * 64 + h * 32 + quad * 8);

  const int kr = tid >> 3;
  const int kc = (tid & 7) ^ (kr & 7);
  const unsigned short* kSrc = Kb + kr * 64 + kc * 8;
  const int vr = tid >> 2;
  const int vc = (tid & 3) ^ (vr & 3) ^ ((vr >> 2) & 3);
  const unsigned short* vSrc = Vb + vr * 1024 + vc * 8;

  floatx4 oacc[2][4];
#pragma unroll
  for (int t = 0; t < 2; t++)
#pragma unroll
    for (int u = 0; u < 4; u++) oacc[t][u] = (floatx4){0.f, 0.f, 0.f, 0.f};
  float lrun[2][4] = {{0.f, 0.f, 0.f, 0.f}, {0.f, 0.f, 0.f, 0.f}};

  async_ld16(kSrc, (char*)&lK[0][0] + wave * 1024);
  async_ld16(vSrc, (char*)&lV[0][0] + wave * 1024);

  const int vca = quad ^ (l16 & 3) ^ ((l16 >> 2) & 3);

  for (int ks = 0; ks < 1024; ks += 32) {
    const int buf = (ks >> 5) & 1;
    __syncthreads();
    const int kn = ks + 32;
    if (kn < 1024) {
      async_ld16(kSrc + kn * 64, (char*)&lK[buf ^ 1][0] + wave * 1024);
      async_ld16(vSrc + kn,      (char*)&lV[buf ^ 1][0] + wave * 1024);
    }
    short8 kf[2][2];
#pragma unroll
    for (int i = 0; i < 2; i++)
#pragma unroll
      for (int h = 0; h < 2; h++) {
        const int gr = (i * 16 + l16) * 8 + ((h * 4 + quad) ^ (l16 & 7));
        kf[i][h] = *(const short8*)(&lK[buf][gr * 8]);
      }
    floatx4 sres[2][2];
#pragma unroll
    for (int t = 0; t < 2; t++)
#pragma unroll
      for (int i = 0; i < 2; i++) {
        const floatx4 z = {0.f, 0.f, 0.f, 0.f};
        floatx4 a = __builtin_amdgcn_mfma_f32_16x16x32_bf16(qf[t][0], kf[i][0], z, 0, 0, 0);
        sres[t][i] = __builtin_amdgcn_mfma_f32_16x16x32_bf16(qf[t][1], kf[i][1], a, 0, 0, 0);
      }
#pragma unroll
    for (int t = 0; t < 2; t++)
#pragma unroll
      for (int r = 0; r < 4; r++) {
        const float p0 = fast_exp2(sres[t][0][r]);
        const float p1 = fast_exp2(sres[t][1][r]);
        lrun[t][r] += p0 + p1;
        P[wave][t][quad * 4 + r][l16] = p0;
        P[wave][t][quad * 4 + r][16 + l16] = p1;
      }
    short8 vf[4];
#pragma unroll
    for (int u = 0; u < 4; u++)
      vf[u] = *(const short8*)(&lV[buf][((u * 16 + l16) * 4 + vca) * 8]);
    short8 pf[2];
#pragma unroll
    for (int t = 0; t < 2; t++) {
      const float* pr = &P[wave][t][l16][quad * 8];
      const floatx4 pa = *(const floatx4*)pr;
      const floatx4 pb = *(const floatx4*)(pr + 4);
      pf[t][0] = (short)f2bf(pa[0]); pf[t][1] = (short)f2bf(pa[1]);
      pf[t][2] = (short)f2bf(pa[2]); pf[t][3] = (short)f2bf(pa[3]);
      pf[t][4] = (short)f2bf(pb[0]); pf[t][5] = (short)f2bf(pb[1]);
      pf[t][6] = (short)f2bf(pb[2]); pf[t][7] = (short)f2bf(pb[3]);
    }
#pragma unroll
    for (int t = 0; t < 2; t++)
#pragma unroll
      for (int u = 0; u < 4; u++)
        oacc[t][u] = __builtin_amdgcn_mfma_f32_16x16x32_bf16(pf[t], vf[u], oacc[t][u], 0, 0, 0);
  }

  const int b = bh >> 4, h = bh & 15;
#pragma unroll
  for (int t = 0; t < 2; t++) {
#pragma unroll
    for (int r = 0; r < 4; r++) {
      float lr = lrun[t][r];
      lr += __shfl_xor(lr, 1);
      lr += __shfl_xor(lr, 2);
      lr += __shfl_xor(lr, 4);
      lr += __shfl_xor(lr, 8);
      const float linv = 1.0f / lr;
#pragma unroll
      for (int u = 0; u < 4; u++) {
        O[((long)b * 1024 + q0 + t * 16 + quad * 4 + r) * 1024 + h * 64 + u * 16 + l16] =
            f2bf(oacc[t][u][r] * linv);
      }
    }
  }
}

// ---------------------------------------------------------------------------
extern "C" void kernel_launch(void* const* d_in, const int* in_sizes, int n_in,
                              void* d_out, int out_size, void* d_ws, size_t ws_size,
                              hipStream_t stream) {
  const float* x      = (const float*)d_in[0];
  const float* ln1_g  = (const float*)d_in[1];
  const float* ln1_b  = (const float*)d_in[2];
  const float* ln2_g  = (const float*)d_in[3];
  const float* ln2_b  = (const float*)d_in[4];
  const float* qkv_w  = (const float*)d_in[5];
  const float* q_bias = (const float*)d_in[6];
  const float* v_bias = (const float*)d_in[7];
  const float* proj_w = (const float*)d_in[8];
  const float* proj_b = (const float*)d_in[9];
  const float* fc1_w  = (const float*)d_in[10];
  const float* fc1_b  = (const float*)d_in[11];
  const float* fc2_w  = (const float*)d_in[12];
  const float* fc2_b  = (const float*)d_in[13];
  float* out = (float*)d_out;

  char* ws = (char*)d_ws;
  unsigned short* Wqkv  = (unsigned short*)(ws);              //  6 MB
  unsigned short* Wproj = (unsigned short*)(ws + 6291456);    //  2 MB
  unsigned short* Wfc1  = (unsigned short*)(ws + 8388608);    //  8 MB
  unsigned short* Wfc2  = (unsigned short*)(ws + 16777216);   //  8 MB
  float*          X1    = (float*)        (ws + 25165824);    // 32 MB fp32
  unsigned short* Hbuf  = (unsigned short*)(ws + 58720256);   // 16 MB
  unsigned short* Qbuf  = (unsigned short*)(ws + 75497472);   // 16 MB
  unsigned short* Kbuf  = (unsigned short*)(ws + 92274688);   // 16 MB
  unsigned short* Vtbuf = (unsigned short*)(ws + 109051904);  // 16 MB
  unsigned short* Obuf  = (unsigned short*)(ws + 125829120);  // 16 MB
  unsigned short* ACT   = Qbuf;  // reuse dead Q/K/Vt/O region: 64 MB

  // weights -> bf16
  cvt_bf16<<<3072 * 1024 / 1024, 256, 0, stream>>>(qkv_w, Wqkv);
  cvt_bf16<<<1024 * 1024 / 1024, 256, 0, stream>>>(proj_w, Wproj);
  cvt_bf16<<<4096 * 1024 / 1024, 256, 0, stream>>>(fc1_w, Wfc1);
  cvt_bf16<<<4096 * 1024 / 1024, 256, 0, stream>>>(fc2_w, Wfc2);

  // LN1
  ln_bf16<<<8192, 256, 0, stream>>>(x, ln1_g, ln1_b, Hbuf);
  // QKV gemm + scatter (256^2 8-wave): 32 m-tiles x 12 n-tiles = 384 blocks
  gemm8<0><<<384, 512, 0, stream>>>(Hbuf, Wqkv, 8192, 3072, 1024,
                                    q_bias, v_bias, nullptr,
                                    Qbuf, Kbuf, Vtbuf);
  // attention
  attn<<<1024, 256, 0, stream>>>(Qbuf, Kbuf, Vtbuf, Obuf);
  // proj + residual -> X1 (fp32)
  gemm_bt<1><<<8 * 64, 256, 0, stream>>>(Obuf, Wproj, 8192, 1024, 1024,
                                         proj_b, nullptr, x,
                                         X1, nullptr, nullptr);
  // LN2
  ln_bf16<<<8192, 256, 0, stream>>>(X1, ln2_g, ln2_b, Hbuf);
  // fc1 + gelu -> ACT (bf16): 32 x 16 = 512 blocks
  gemm8<2><<<512, 512, 0, stream>>>(Hbuf, Wfc1, 8192, 4096, 1024,
                                    fc1_b, nullptr, nullptr,
                                    ACT, nullptr, nullptr);
  // fc2 + residual -> out (fp32)
  gemm_bt<1><<<8 * 64, 256, 0, stream>>>(ACT, Wfc2, 8192, 1024, 4096,
                                         fc2_b, nullptr, X1,
                                         out, nullptr, nullptr);
  (void)in_sizes; (void)n_in; (void)out_size; (void)ws_size;
}

// Round 2
// 590.408 us; speedup vs baseline: 1.0201x; 1.0201x over previous
//
#include <hip/hip_runtime.h>
#include <hip/hip_bf16.h>

// ---------------------------------------------------------------------------
// Transformer block (B=8, N=1024, D=1024, H=16, HD=64, FF=4096), fp32 in/out.
// bf16 MFMA GEMMs (fp32 accum, XCD-striped, double-buffered LDS, swizzled
// granules -> conflict-free ds_read_b128), flash attention (LDS-shared K/V,
// no-shift softmax), fused epilogues.
// R2: reverted gemm8 (4-phase 256^2 regressed: 1 block/CU, no TLP, lockstep
// barriers exposed memory latency -> 450 TF vs 600 TF for 2-phase 128^2).
// Fused 4x cvt_bf16 + LN1 into one `prep` kernel: dispatch-time accounting
// shows ~155 us of per-iteration overhead not inside any dispatch (~14 us x
// 11 launches); this round removes 4 boundaries to isolate that theory.
// ---------------------------------------------------------------------------

typedef __attribute__((ext_vector_type(8))) short short8;
typedef __attribute__((ext_vector_type(4))) float floatx4;

__device__ __forceinline__ unsigned short f2bf(float f) {
  union { __hip_bfloat16 h; unsigned short u; } cv;
  cv.h = __float2bfloat16(f);
  return cv.u;
}

// 2^x via the native v_exp_f32 instruction (avoid glibc __exp2f macro clash)
__device__ __forceinline__ float fast_exp2(float x) {
  return __builtin_amdgcn_exp2f(x);
}

__device__ __forceinline__ void async_ld16(const void* g, void* l) {
  __builtin_amdgcn_global_load_lds(
      (const __attribute__((address_space(1))) unsigned int*)g,
      (__attribute__((address_space(3))) unsigned int*)l, 16, 0, 0);
}

// ---------------- LayerNorm device body (one 256-thr block per row) --------
__device__ __forceinline__ void ln_row(const float* __restrict__ x,
                                       const float* __restrict__ g,
                                       const float* __restrict__ b,
                                       unsigned short* __restrict__ out,
                                       int row, int tid) {
  const float4 v = ((const float4*)(x + (long)row * 1024))[tid];
  float s = v.x + v.y + v.z + v.w;
  float ss = v.x * v.x + v.y * v.y + v.z * v.z + v.w * v.w;
#pragma unroll
  for (int off = 1; off < 64; off <<= 1) {
    s += __shfl_xor(s, off);
    ss += __shfl_xor(ss, off);
  }
  __shared__ float red[8];
  const int wave = tid >> 6, lane = tid & 63;
  if (lane == 0) { red[wave] = s; red[4 + wave] = ss; }
  __syncthreads();
  if (tid == 0) {
    red[0] = red[0] + red[1] + red[2] + red[3];
    red[4] = red[4] + red[5] + red[6] + red[7];
  }
  __syncthreads();
  const float mu = red[0] * (1.f / 1024.f);
  const float var = red[4] * (1.f / 1024.f) - mu * mu;
  const float rstd = rsqrtf(var + 1e-5f);
  const int c = tid * 4;
  ushort4 o;
  o.x = f2bf((v.x - mu) * rstd * g[c + 0] + b[c + 0]);
  o.y = f2bf((v.y - mu) * rstd * g[c + 1] + b[c + 1]);
  o.z = f2bf((v.z - mu) * rstd * g[c + 2] + b[c + 2]);
  o.w = f2bf((v.w - mu) * rstd * g[c + 3] + b[c + 3]);
  ((ushort4*)(out + (long)row * 1024))[tid] = o;
}

__global__ __launch_bounds__(256) void ln_bf16(const float* __restrict__ x,
                                               const float* __restrict__ g,
                                               const float* __restrict__ b,
                                               unsigned short* __restrict__ out) {
  ln_row(x, g, b, out, blockIdx.x, threadIdx.x);
}

// ---------------- Fused prologue: LN1 (8192 blocks) + weight cvt (12288) ---
// All five pieces are independent; fusing removes 4 kernel-launch boundaries.
__global__ __launch_bounds__(256) void prep(
    const float* __restrict__ x, const float* __restrict__ g,
    const float* __restrict__ b, unsigned short* __restrict__ outLN,
    const float* __restrict__ w_qkv, unsigned short* __restrict__ o_qkv,
    const float* __restrict__ w_proj, unsigned short* __restrict__ o_proj,
    const float* __restrict__ w_fc1, unsigned short* __restrict__ o_fc1,
    const float* __restrict__ w_fc2, unsigned short* __restrict__ o_fc2) {
  const int bidx = blockIdx.x;
  const int tid = threadIdx.x;
  if (bidx < 8192) {
    ln_row(x, g, b, outLN, bidx, tid);
    return;
  }
  int c = bidx - 8192;
  const float* src;
  unsigned short* dst;
  if (c < 3072) { src = w_qkv; dst = o_qkv; }
  else if (c < 4096) { src = w_proj; dst = o_proj; c -= 3072; }
  else if (c < 8192) { src = w_fc1; dst = o_fc1; c -= 4096; }
  else { src = w_fc2; dst = o_fc2; c -= 8192; }
  const long i = ((long)c * 256 + tid) * 4;
  const float4 v = *(const float4*)(src + i);
  ushort4 o;
  o.x = f2bf(v.x); o.y = f2bf(v.y); o.z = f2bf(v.z); o.w = f2bf(v.w);
  *(ushort4*)(dst + i) = o;
}

// ---------------- GEMM: C[M,N] = A[M,K] @ B[N,K]^T, fused epilogues --------
// 1-D grid of (N/128)*64 blocks. XCD-aware decode (dispatch round-robin:
// xcd = bid & 7): each XCD owns 8 contiguous m-tiles (2 MB A-stripe,
// L2-resident) and sweeps n-tiles; co-resident blocks share B k-slices
// through L2. Double-buffered LDS staging (1 barrier/iter).
// LDS granule swizzle: granule for (row, kc) stored at (row, kc^((row>>1)&3))
// -- applied on the GLOBAL source address since global_load_lds's LDS side is
// lane-contiguous. Fragment reads then hit banks in {r, r+8} pairs = 2-way
// conflicts only, which are free (m136).
// MODE 0: QKV scatter  (out0=Q [bh,n,hd] *scale*log2e+qb, out1=K [bh,n,hd],
//                       out2=Vt [bh,hd,n] +vb)
// MODE 1: fp32 out = resid + acc + bias   (proj / fc2)
// MODE 2: bf16 out = gelu(acc + bias)     (fc1)
#define BM 128
#define BN 128
#define BK 32

template <int MODE>
__global__ __launch_bounds__(256) void gemm_bt(
    const unsigned short* __restrict__ A, const unsigned short* __restrict__ B,
    int M, int N, int Kd,
    const float* __restrict__ b0, const float* __restrict__ b1,
    const float* __restrict__ resid,
    void* __restrict__ out0, void* __restrict__ out1, void* __restrict__ out2) {
  __shared__ unsigned short lA[2][BM * BK];
  __shared__ unsigned short lB[2][BN * BK];
  const int tid = threadIdx.x;
  const int wave = tid >> 6, lane = tid & 63;
  const int l16 = lane & 15, quad = lane >> 4;
  const int wr = wave >> 1, wc = wave & 1;
  // XCD-striped decode (M/128 == 64 rows of tiles; 8 per XCD)
  const int bid = blockIdx.x;
  const int xcd = bid & 7;
  const int s = bid >> 3;
  const long m0 = (long)(xcd * 8 + (s & 7)) * BM;
  const long n0 = (long)(s >> 3) * BN;

  // staging addresses: thread stages granule tid (+256) of each tile,
  // with the bank-swizzle folded into the global column
  const int row = tid >> 2;
  const int kc = (tid & 3) ^ ((row >> 1) & 3);  // swizzled granule column
  const unsigned short* aSrc = A + (m0 + row) * Kd + kc * 8;
  const unsigned short* bSrc = B + (n0 + row) * Kd + kc * 8;
  // note: ((row+64)>>1)&3 == ((row>>1)&3), so the +64-row granule reuses kc
  const int ldsOff0 = wave * 1024;            // bytes: (wave*64)*16
  const int ldsOff1 = wave * 1024 + 4096;     // bytes: (+256 granules)

  floatx4 acc[4][4];
#pragma unroll
  for (int i = 0; i < 4; i++)
#pragma unroll
    for (int j = 0; j < 4; j++) acc[i][j] = (floatx4){0.f, 0.f, 0.f, 0.f};

  // prologue: stage buffer 0
  async_ld16(aSrc, (char*)&lA[0][0] + ldsOff0);
  async_ld16(aSrc + 64 * Kd, (char*)&lA[0][0] + ldsOff1);
  async_ld16(bSrc, (char*)&lB[0][0] + ldsOff0);
  async_ld16(bSrc + 64 * Kd, (char*)&lB[0][0] + ldsOff1);

  // per-lane swizzled read granules (fragment row = base + l16)
  const int sw = ((l16 >> 1) & 3);  // (row>>1)&3 for row = (multiple of 16)+l16

  for (int k0 = 0; k0 < Kd; k0 += BK) {
    const int buf = (k0 >> 5) & 1;
    __syncthreads();  // drains this buffer's staged loads (vmcnt(0) @ barrier)
    const int kn = k0 + BK;
    if (kn < Kd) {
      async_ld16(aSrc + kn, (char*)&lA[buf ^ 1][0] + ldsOff0);
      async_ld16(aSrc + 64 * Kd + kn, (char*)&lA[buf ^ 1][0] + ldsOff1);
      async_ld16(bSrc + kn, (char*)&lB[buf ^ 1][0] + ldsOff0);
      async_ld16(bSrc + 64 * Kd + kn, (char*)&lB[buf ^ 1][0] + ldsOff1);
    }
    short8 af[4], bfv[4];
#pragma unroll
    for (int mi = 0; mi < 4; mi++) {
      const int r = wr * 64 + mi * 16 + l16;
      af[mi] = *(const short8*)(&lA[buf][(r * 4 + (quad ^ sw)) * 8]);
    }
#pragma unroll
    for (int ni = 0; ni < 4; ni++) {
      const int r = wc * 64 + ni * 16 + l16;
      bfv[ni] = *(const short8*)(&lB[buf][(r * 4 + (quad ^ sw)) * 8]);
    }
#pragma unroll
    for (int mi = 0; mi < 4; mi++)
#pragma unroll
      for (int ni = 0; ni < 4; ni++)
        acc[mi][ni] = __builtin_amdgcn_mfma_f32_16x16x32_bf16(
            af[mi], bfv[ni], acc[mi][ni], 0, 0, 0);
  }

#pragma unroll
  for (int mi = 0; mi < 4; mi++) {
    const long rbase = m0 + wr * 64 + mi * 16 + quad * 4;
#pragma unroll
    for (int ni = 0; ni < 4; ni++) {
      const long cg = n0 + wc * 64 + ni * 16 + l16;
#pragma unroll
      for (int reg = 0; reg < 4; reg++) {
        const long rr = rbase + reg;
        const float val = acc[mi][ni][reg];
        if (MODE == 0) {
          const int which = (int)(cg >> 10);
          const int col = (int)(cg & 1023);
          const int bidx = (int)(rr >> 10), t = (int)(rr & 1023);
          const int head = col >> 6, hd = col & 63;
          const long bh = bidx * 16 + head;
          if (which == 0) {
            // fold softmax scale (1/8) AND log2(e) into Q so attn can use
            // exp2 (native v_exp_f32) with no shift.
            ((unsigned short*)out0)[(bh * 1024 + t) * 64 + hd] =
                f2bf((val + b0[col]) * 0.1803368801111244f);
          } else if (which == 1) {
            ((unsigned short*)out1)[(bh * 1024 + t) * 64 + hd] = f2bf(val);
          } else {
            ((unsigned short*)out2)[(bh * 64 + hd) * 1024 + t] =
                f2bf(val + b1[col]);
          }
        } else if (MODE == 1) {
          const long idx = rr * N + cg;
          ((float*)out0)[idx] = resid[idx] + val + b0[cg];
        } else {
          const float u = val + b0[cg];
          const float gl = 0.5f * u * (1.0f + erff(u * 0.70710678118f));
          ((unsigned short*)out0)[rr * N + cg] = f2bf(gl);
        }
      }
    }
  }
}

// ---------------- Flash attention, LDS-shared K/V --------------------------
// 1-D grid of 1024 blocks, XCD-striped: xcd = bid&7 owns 16 bh; all 8
// q-blocks of a bh land on one XCD so K/V k-slices are L2-shared (per-XCD
// K/V working set 4 MB). Block = 256 threads = 4 waves; each wave owns
// 32 Q rows; the block shares K/V tiles staged in LDS (global_load_lds,
// double-buffered, 1 barrier/iter). K granules (16B) are XOR-swizzled on
// the GLOBAL side (LDS side of global_load_lds is lane-contiguous) so
// ds_read_b128 fragment reads are <=2-way bank conflicted (free).
// Q pre-scaled by 0.125*log2e; un-shifted softmax (scores are tiny).
__global__ __launch_bounds__(256) void attn(const unsigned short* __restrict__ Q,
                                            const unsigned short* __restrict__ Kc,
                                            const unsigned short* __restrict__ Vt,
                                            unsigned short* __restrict__ O) {
  __shared__ unsigned short lK[2][2048];   // 4 KB per buffer: 32 kv x 64 hd
  __shared__ unsigned short lV[2][2048];   // 4 KB per buffer: 64 hd x 32 kv
  __shared__ float P[4][2][16][34];        // per-wave, per-Q-tile P slab
  const int tid = threadIdx.x;
  const int wave = tid >> 6, lane = tid & 63;
  const int l16 = lane & 15, quad = lane >> 4;
  const int bid = blockIdx.x;
  const int xcd = bid & 7;
  const int sl = bid >> 3;
  const int bh = xcd * 16 + (sl & 15);
  const int q0 = (sl >> 4) * 128 + wave * 32;
  const unsigned short* Qb = Q + ((long)bh * 1024 + q0) * 64;
  const unsigned short* Kb = Kc + (long)bh * 65536;
  const unsigned short* Vb = Vt + (long)bh * 65536;

  // Q fragments: 2 tiles x 2 k-halves
  short8 qf[2][2];
#pragma unroll
  for (int t = 0; t < 2; t++)
#pragma unroll
    for (int h = 0; h < 2; h++)
      qf[t][h] = *(const short8*)(Qb + (t * 16 + l16) * 64 + h * 32 + quad * 8);

  // staging source addresses (thread t stages LDS granule t of each tile)
  const int kr = tid >> 3;                                  // K row 0..31
  const int kc = (tid & 7) ^ (kr & 7);                      // swizzled col
  const unsigned short* kSrc = Kb + kr * 64 + kc * 8;
  const int vr = tid >> 2;                                  // Vt row 0..63
  const int vc = (tid & 3) ^ (vr & 3) ^ ((vr >> 2) & 3);    // swizzled col
  const unsigned short* vSrc = Vb + vr * 1024 + vc * 8;

  floatx4 oacc[2][4];
#pragma unroll
  for (int t = 0; t < 2; t++)
#pragma unroll
    for (int u = 0; u < 4; u++) oacc[t][u] = (floatx4){0.f, 0.f, 0.f, 0.f};
  float lrun[2][4] = {{0.f, 0.f, 0.f, 0.f}, {0.f, 0.f, 0.f, 0.f}};

  // prologue: stage buffer 0
  async_ld16(kSrc, (char*)&lK[0][0] + wave * 1024);
  async_ld16(vSrc, (char*)&lV[0][0] + wave * 1024);

  const int vca = quad ^ (l16 & 3) ^ ((l16 >> 2) & 3);  // V read swizzle

  for (int ks = 0; ks < 1024; ks += 32) {
    const int buf = (ks >> 5) & 1;
    __syncthreads();  // drains this buffer's staged loads (vmcnt(0) @ barrier)
    const int kn = ks + 32;
    if (kn < 1024) {
      async_ld16(kSrc + kn * 64, (char*)&lK[buf ^ 1][0] + wave * 1024);
      async_ld16(vSrc + kn,      (char*)&lV[buf ^ 1][0] + wave * 1024);
    }
    // K fragments (shared by both Q tiles)
    short8 kf[2][2];
#pragma unroll
    for (int i = 0; i < 2; i++)
#pragma unroll
      for (int h = 0; h < 2; h++) {
        const int gr = (i * 16 + l16) * 8 + ((h * 4 + quad) ^ (l16 & 7));
        kf[i][h] = *(const short8*)(&lK[buf][gr * 8]);
      }
    // QK^T
    floatx4 s[2][2];
#pragma unroll
    for (int t = 0; t < 2; t++)
#pragma unroll
      for (int i = 0; i < 2; i++) {
        const floatx4 z = {0.f, 0.f, 0.f, 0.f};
        floatx4 a = __builtin_amdgcn_mfma_f32_16x16x32_bf16(qf[t][0], kf[i][0], z, 0, 0, 0);
        s[t][i] = __builtin_amdgcn_mfma_f32_16x16x32_bf16(qf[t][1], kf[i][1], a, 0, 0, 0);
      }
    // softmax numerators + P slabs
#pragma unroll
    for (int t = 0; t < 2; t++)
#pragma unroll
      for (int r = 0; r < 4; r++) {
        const float p0 = fast_exp2(s[t][0][r]);
        const float p1 = fast_exp2(s[t][1][r]);
        lrun[t][r] += p0 + p1;
        P[wave][t][quad * 4 + r][l16] = p0;
        P[wave][t][quad * 4 + r][16 + l16] = p1;
      }
    // V fragments (shared by both Q tiles)
    short8 vf[4];
#pragma unroll
    for (int u = 0; u < 4; u++)
      vf[u] = *(const short8*)(&lV[buf][((u * 16 + l16) * 4 + vca) * 8]);
    // P: C-layout -> A-operand layout via private LDS slab (intra-wave)
    short8 pf[2];
#pragma unroll
    for (int t = 0; t < 2; t++) {
      const float* pr = &P[wave][t][l16][quad * 8];
      const floatx4 pa = *(const floatx4*)pr;
      const floatx4 pb = *(const floatx4*)(pr + 4);
      pf[t][0] = (short)f2bf(pa[0]); pf[t][1] = (short)f2bf(pa[1]);
      pf[t][2] = (short)f2bf(pa[2]); pf[t][3] = (short)f2bf(pa[3]);
      pf[t][4] = (short)f2bf(pb[0]); pf[t][5] = (short)f2bf(pb[1]);
      pf[t][6] = (short)f2bf(pb[2]); pf[t][7] = (short)f2bf(pb[3]);
    }
    // P @ V
#pragma unroll
    for (int t = 0; t < 2; t++)
#pragma unroll
      for (int u = 0; u < 4; u++)
        oacc[t][u] = __builtin_amdgcn_mfma_f32_16x16x32_bf16(pf[t], vf[u], oacc[t][u], 0, 0, 0);
  }

  // final denominator reduce across the 16 kv-lanes
  const int b = bh >> 4, h = bh & 15;
#pragma unroll
  for (int t = 0; t < 2; t++) {
#pragma unroll
    for (int r = 0; r < 4; r++) {
      float lr = lrun[t][r];
      lr += __shfl_xor(lr, 1);
      lr += __shfl_xor(lr, 2);
      lr += __shfl_xor(lr, 4);
      lr += __shfl_xor(lr, 8);
      const float linv = 1.0f / lr;
#pragma unroll
      for (int u = 0; u < 4; u++) {
        O[((long)b * 1024 + q0 + t * 16 + quad * 4 + r) * 1024 + h * 64 + u * 16 + l16] =
            f2bf(oacc[t][u][r] * linv);
      }
    }
  }
}

// ---------------------------------------------------------------------------
extern "C" void kernel_launch(void* const* d_in, const int* in_sizes, int n_in,
                              void* d_out, int out_size, void* d_ws, size_t ws_size,
                              hipStream_t stream) {
  const float* x      = (const float*)d_in[0];
  const float* ln1_g  = (const float*)d_in[1];
  const float* ln1_b  = (const float*)d_in[2];
  const float* ln2_g  = (const float*)d_in[3];
  const float* ln2_b  = (const float*)d_in[4];
  const float* qkv_w  = (const float*)d_in[5];
  const float* q_bias = (const float*)d_in[6];
  const float* v_bias = (const float*)d_in[7];
  const float* proj_w = (const float*)d_in[8];
  const float* proj_b = (const float*)d_in[9];
  const float* fc1_w  = (const float*)d_in[10];
  const float* fc1_b  = (const float*)d_in[11];
  const float* fc2_w  = (const float*)d_in[12];
  const float* fc2_b  = (const float*)d_in[13];
  float* out = (float*)d_out;

  char* ws = (char*)d_ws;
  unsigned short* Wqkv  = (unsigned short*)(ws);              //  6 MB
  unsigned short* Wproj = (unsigned short*)(ws + 6291456);    //  2 MB
  unsigned short* Wfc1  = (unsigned short*)(ws + 8388608);    //  8 MB
  unsigned short* Wfc2  = (unsigned short*)(ws + 16777216);   //  8 MB
  float*          X1    = (float*)        (ws + 25165824);    // 32 MB fp32
  unsigned short* Hbuf  = (unsigned short*)(ws + 58720256);   // 16 MB
  unsigned short* Qbuf  = (unsigned short*)(ws + 75497472);   // 16 MB
  unsigned short* Kbuf  = (unsigned short*)(ws + 92274688);   // 16 MB
  unsigned short* Vtbuf = (unsigned short*)(ws + 109051904);  // 16 MB
  unsigned short* Obuf  = (unsigned short*)(ws + 125829120);  // 16 MB
  unsigned short* ACT   = Qbuf;  // reuse dead Q/K/Vt/O region: 64 MB

  // fused prologue: LN1 (blocks 0..8191) + all 4 weight conversions
  prep<<<20480, 256, 0, stream>>>(x, ln1_g, ln1_b, Hbuf,
                                  qkv_w, Wqkv, proj_w, Wproj,
                                  fc1_w, Wfc1, fc2_w, Wfc2);
  // QKV gemm + scatter (q scaled by 0.125*log2e, v -> transposed)
  gemm_bt<0><<<24 * 64, 256, 0, stream>>>(Hbuf, Wqkv, 8192, 3072, 1024,
                                          q_bias, v_bias, nullptr,
                                          Qbuf, Kbuf, Vtbuf);
  // attention
  attn<<<1024, 256, 0, stream>>>(Qbuf, Kbuf, Vtbuf, Obuf);
  // proj + residual -> X1 (fp32)
  gemm_bt<1><<<8 * 64, 256, 0, stream>>>(Obuf, Wproj, 8192, 1024, 1024,
                                         proj_b, nullptr, x,
                                         X1, nullptr, nullptr);
  // LN2
  ln_bf16<<<8192, 256, 0, stream>>>(X1, ln2_g, ln2_b, Hbuf);
  // fc1 + gelu -> ACT (bf16)
  gemm_bt<2><<<32 * 64, 256, 0, stream>>>(Hbuf, Wfc1, 8192, 4096, 1024,
                                          fc1_b, nullptr, nullptr,
                                          ACT, nullptr, nullptr);
  // fc2 + residual -> out (fp32)
  gemm_bt<1><<<8 * 64, 256, 0, stream>>>(ACT, Wfc2, 8192, 1024, 4096,
                                         fc2_b, nullptr, X1,
                                         out, nullptr, nullptr);
  (void)in_sizes; (void)n_in; (void)out_size; (void)ws_size;
}

// Round 3
// 565.923 us; speedup vs baseline: 1.0643x; 1.0433x over previous
//
#include <hip/hip_runtime.h>
#include <hip/hip_bf16.h>

// ---------------------------------------------------------------------------
// Transformer block (B=8, N=1024, D=1024, H=16, HD=64, FF=4096), fp32 in/out.
// bf16 MFMA GEMMs (fp32 accum, XCD-striped, double-buffered LDS, swizzled
// granules -> conflict-free ds_read_b128), flash attention (LDS-shared K/V,
// no-shift softmax), fused epilogues.
// R3: BK 32->64 in gemm_bt as TWO independent BK=32 sub-tiles per buffer
// (identical granule layout/swizzle -> keeps measured-zero bank conflicts).
// Halves the per-block __syncthreads count (32->16 full vmcnt drains).
// Launch structure reverted to R0 (separate cvt/ln) -- R2's prep fusion was
// net-neutral and confounded the per-kernel timing (QKV +43us, same bytes).
// ---------------------------------------------------------------------------

typedef __attribute__((ext_vector_type(8))) short short8;
typedef __attribute__((ext_vector_type(4))) float floatx4;

__device__ __forceinline__ unsigned short f2bf(float f) {
  union { __hip_bfloat16 h; unsigned short u; } cv;
  cv.h = __float2bfloat16(f);
  return cv.u;
}

// 2^x via the native v_exp_f32 instruction (avoid glibc __exp2f macro clash)
__device__ __forceinline__ float fast_exp2(float x) {
  return __builtin_amdgcn_exp2f(x);
}

__device__ __forceinline__ void async_ld16(const void* g, void* l) {
  __builtin_amdgcn_global_load_lds(
      (const __attribute__((address_space(1))) unsigned int*)g,
      (__attribute__((address_space(3))) unsigned int*)l, 16, 0, 0);
}

// ---------------- fp32 -> bf16 weight conversion (4 elems/thread) ----------
__global__ __launch_bounds__(256) void cvt_bf16(const float* __restrict__ in,
                                                unsigned short* __restrict__ out) {
  const long i = ((long)blockIdx.x * 256 + threadIdx.x) * 4;
  const float4 v = *(const float4*)(in + i);
  ushort4 o;
  o.x = f2bf(v.x); o.y = f2bf(v.y); o.z = f2bf(v.z); o.w = f2bf(v.w);
  *(ushort4*)(out + i) = o;
}

// ---------------- LayerNorm: fp32 row -> bf16 row (one block per row) ------
__global__ __launch_bounds__(256) void ln_bf16(const float* __restrict__ x,
                                               const float* __restrict__ g,
                                               const float* __restrict__ b,
                                               unsigned short* __restrict__ out) {
  const int row = blockIdx.x;
  const int tid = threadIdx.x;
  const float4 v = ((const float4*)(x + (long)row * 1024))[tid];
  float s = v.x + v.y + v.z + v.w;
  float ss = v.x * v.x + v.y * v.y + v.z * v.z + v.w * v.w;
#pragma unroll
  for (int off = 1; off < 64; off <<= 1) {
    s += __shfl_xor(s, off);
    ss += __shfl_xor(ss, off);
  }
  __shared__ float red[8];
  const int wave = tid >> 6, lane = tid & 63;
  if (lane == 0) { red[wave] = s; red[4 + wave] = ss; }
  __syncthreads();
  if (tid == 0) {
    red[0] = red[0] + red[1] + red[2] + red[3];
    red[4] = red[4] + red[5] + red[6] + red[7];
  }
  __syncthreads();
  const float mu = red[0] * (1.f / 1024.f);
  const float var = red[4] * (1.f / 1024.f) - mu * mu;
  const float rstd = rsqrtf(var + 1e-5f);
  const int c = tid * 4;
  ushort4 o;
  o.x = f2bf((v.x - mu) * rstd * g[c + 0] + b[c + 0]);
  o.y = f2bf((v.y - mu) * rstd * g[c + 1] + b[c + 1]);
  o.z = f2bf((v.z - mu) * rstd * g[c + 2] + b[c + 2]);
  o.w = f2bf((v.w - mu) * rstd * g[c + 3] + b[c + 3]);
  ((ushort4*)(out + (long)row * 1024))[tid] = o;
}

// ---------------- GEMM: C[M,N] = A[M,K] @ B[N,K]^T, fused epilogues --------
// 1-D grid of (N/128)*64 blocks. XCD-aware decode (dispatch round-robin:
// xcd = bid & 7): each XCD owns 8 contiguous m-tiles (2 MB A-stripe,
// L2-resident) and sweeps n-tiles; co-resident blocks share B k-slices
// through L2. Double-buffered LDS staging, BK=64 per barrier as two BK=32
// sub-tiles (16 barriers over K=1024 instead of 32; each barrier is a full
// vmcnt drain, so halving the count halves the structural stall).
// LDS granule swizzle per sub-tile: granule (row, kc) stored at
// (row, kc^((row>>1)&3)) -- applied on the GLOBAL source address since
// global_load_lds's LDS side is lane-contiguous. Fragment ds_read_b128 then
// hits banks in {r, r+8} pairs = 2-way conflicts only (free; measured 0).
// MODE 0: QKV scatter  (out0=Q [bh,n,hd] *scale*log2e+qb, out1=K [bh,n,hd],
//                       out2=Vt [bh,hd,n] +vb)
// MODE 1: fp32 out = resid + acc + bias   (proj / fc2)
// MODE 2: bf16 out = gelu(acc + bias)     (fc1)
#define BM 128
#define BN 128

template <int MODE>
__global__ __launch_bounds__(256) void gemm_bt(
    const unsigned short* __restrict__ A, const unsigned short* __restrict__ B,
    int M, int N, int Kd,
    const float* __restrict__ b0, const float* __restrict__ b1,
    const float* __restrict__ resid,
    void* __restrict__ out0, void* __restrict__ out1, void* __restrict__ out2) {
  __shared__ unsigned short lA[2][2][BM * 32];   // [buf][k32-sub][tile]
  __shared__ unsigned short lB[2][2][BN * 32];
  const int tid = threadIdx.x;
  const int wave = tid >> 6, lane = tid & 63;
  const int l16 = lane & 15, quad = lane >> 4;
  const int wr = wave >> 1, wc = wave & 1;
  // XCD-striped decode (M/128 == 64 rows of tiles; 8 per XCD)
  const int bid = blockIdx.x;
  const int xcd = bid & 7;
  const int s = bid >> 3;
  const long m0 = (long)(xcd * 8 + (s & 7)) * BM;
  const long n0 = (long)(s >> 3) * BN;

  // staging addresses: thread stages granule tid (+256) of each sub-tile,
  // with the bank-swizzle folded into the global column
  const int row = tid >> 2;
  const int kc = (tid & 3) ^ ((row >> 1) & 3);  // swizzled granule column
  const unsigned short* aSrc = A + (m0 + row) * Kd + kc * 8;
  const unsigned short* bSrc = B + (n0 + row) * Kd + kc * 8;
  // note: ((row+64)>>1)&3 == ((row>>1)&3), so the +64-row granule reuses kc
  const int ldsOff0 = wave * 1024;            // bytes: (wave*64)*16
  const int ldsOff1 = wave * 1024 + 4096;     // bytes: (+256 granules)

  floatx4 acc[4][4];
#pragma unroll
  for (int i = 0; i < 4; i++)
#pragma unroll
    for (int j = 0; j < 4; j++) acc[i][j] = (floatx4){0.f, 0.f, 0.f, 0.f};

  // prologue: stage buffer 0 (both k32 sub-tiles)
#pragma unroll
  for (int sb = 0; sb < 2; sb++) {
    async_ld16(aSrc + sb * 32, (char*)&lA[0][sb][0] + ldsOff0);
    async_ld16(aSrc + 64 * Kd + sb * 32, (char*)&lA[0][sb][0] + ldsOff1);
    async_ld16(bSrc + sb * 32, (char*)&lB[0][sb][0] + ldsOff0);
    async_ld16(bSrc + 64 * Kd + sb * 32, (char*)&lB[0][sb][0] + ldsOff1);
  }

  // per-lane swizzled read granules (fragment row = base + l16)
  const int sw = ((l16 >> 1) & 3);  // (row>>1)&3 for row = (multiple of 16)+l16

  for (int k0 = 0; k0 < Kd; k0 += 64) {
    const int buf = (k0 >> 6) & 1;
    __syncthreads();  // drains this buffer's staged loads (vmcnt(0) @ barrier)
    const int kn = k0 + 64;
    if (kn < Kd) {
#pragma unroll
      for (int sb = 0; sb < 2; sb++) {
        async_ld16(aSrc + kn + sb * 32, (char*)&lA[buf ^ 1][sb][0] + ldsOff0);
        async_ld16(aSrc + 64 * Kd + kn + sb * 32,
                   (char*)&lA[buf ^ 1][sb][0] + ldsOff1);
        async_ld16(bSrc + kn + sb * 32, (char*)&lB[buf ^ 1][sb][0] + ldsOff0);
        async_ld16(bSrc + 64 * Kd + kn + sb * 32,
                   (char*)&lB[buf ^ 1][sb][0] + ldsOff1);
      }
    }
#pragma unroll
    for (int sb = 0; sb < 2; sb++) {
      short8 af[4], bfv[4];
#pragma unroll
      for (int mi = 0; mi < 4; mi++) {
        const int r = wr * 64 + mi * 16 + l16;
        af[mi] = *(const short8*)(&lA[buf][sb][(r * 4 + (quad ^ sw)) * 8]);
      }
#pragma unroll
      for (int ni = 0; ni < 4; ni++) {
        const int r = wc * 64 + ni * 16 + l16;
        bfv[ni] = *(const short8*)(&lB[buf][sb][(r * 4 + (quad ^ sw)) * 8]);
      }
#pragma unroll
      for (int mi = 0; mi < 4; mi++)
#pragma unroll
        for (int ni = 0; ni < 4; ni++)
          acc[mi][ni] = __builtin_amdgcn_mfma_f32_16x16x32_bf16(
              af[mi], bfv[ni], acc[mi][ni], 0, 0, 0);
    }
  }

#pragma unroll
  for (int mi = 0; mi < 4; mi++) {
    const long rbase = m0 + wr * 64 + mi * 16 + quad * 4;
#pragma unroll
    for (int ni = 0; ni < 4; ni++) {
      const long cg = n0 + wc * 64 + ni * 16 + l16;
#pragma unroll
      for (int reg = 0; reg < 4; reg++) {
        const long rr = rbase + reg;
        const float val = acc[mi][ni][reg];
        if (MODE == 0) {
          const int which = (int)(cg >> 10);
          const int col = (int)(cg & 1023);
          const int bidx = (int)(rr >> 10), t = (int)(rr & 1023);
          const int head = col >> 6, hd = col & 63;
          const long bh = bidx * 16 + head;
          if (which == 0) {
            // fold softmax scale (1/8) AND log2(e) into Q so attn can use
            // exp2 (native v_exp_f32) with no shift.
            ((unsigned short*)out0)[(bh * 1024 + t) * 64 + hd] =
                f2bf((val + b0[col]) * 0.1803368801111244f);
          } else if (which == 1) {
            ((unsigned short*)out1)[(bh * 1024 + t) * 64 + hd] = f2bf(val);
          } else {
            ((unsigned short*)out2)[(bh * 64 + hd) * 1024 + t] =
                f2bf(val + b1[col]);
          }
        } else if (MODE == 1) {
          const long idx = rr * N + cg;
          ((float*)out0)[idx] = resid[idx] + val + b0[cg];
        } else {
          const float u = val + b0[cg];
          const float gl = 0.5f * u * (1.0f + erff(u * 0.70710678118f));
          ((unsigned short*)out0)[rr * N + cg] = f2bf(gl);
        }
      }
    }
  }
}

// ---------------- Flash attention, LDS-shared K/V --------------------------
// 1-D grid of 1024 blocks, XCD-striped: xcd = bid&7 owns 16 bh; all 8
// q-blocks of a bh land on one XCD so K/V k-slices are L2-shared (per-XCD
// K/V working set 4 MB). Block = 256 threads = 4 waves; each wave owns
// 32 Q rows; the block shares K/V tiles staged in LDS (global_load_lds,
// double-buffered, 1 barrier/iter). K granules (16B) are XOR-swizzled on
// the GLOBAL side (LDS side of global_load_lds is lane-contiguous) so
// ds_read_b128 fragment reads are <=2-way bank conflicted (free).
// Q pre-scaled by 0.125*log2e; un-shifted softmax (scores are tiny).
__global__ __launch_bounds__(256) void attn(const unsigned short* __restrict__ Q,
                                            const unsigned short* __restrict__ Kc,
                                            const unsigned short* __restrict__ Vt,
                                            unsigned short* __restrict__ O) {
  __shared__ unsigned short lK[2][2048];   // 4 KB per buffer: 32 kv x 64 hd
  __shared__ unsigned short lV[2][2048];   // 4 KB per buffer: 64 hd x 32 kv
  __shared__ float P[4][2][16][34];        // per-wave, per-Q-tile P slab
  const int tid = threadIdx.x;
  const int wave = tid >> 6, lane = tid & 63;
  const int l16 = lane & 15, quad = lane >> 4;
  const int bid = blockIdx.x;
  const int xcd = bid & 7;
  const int sl = bid >> 3;
  const int bh = xcd * 16 + (sl & 15);
  const int q0 = (sl >> 4) * 128 + wave * 32;
  const unsigned short* Qb = Q + ((long)bh * 1024 + q0) * 64;
  const unsigned short* Kb = Kc + (long)bh * 65536;
  const unsigned short* Vb = Vt + (long)bh * 65536;

  // Q fragments: 2 tiles x 2 k-halves
  short8 qf[2][2];
#pragma unroll
  for (int t = 0; t < 2; t++)
#pragma unroll
    for (int h = 0; h < 2; h++)
      qf[t][h] = *(const short8*)(Qb + (t * 16 + l16) * 64 + h * 32 + quad * 8);

  // staging source addresses (thread t stages LDS granule t of each tile)
  const int kr = tid >> 3;                                  // K row 0..31
  const int kc = (tid & 7) ^ (kr & 7);                      // swizzled col
  const unsigned short* kSrc = Kb + kr * 64 + kc * 8;
  const int vr = tid >> 2;                                  // Vt row 0..63
  const int vc = (tid & 3) ^ (vr & 3) ^ ((vr >> 2) & 3);    // swizzled col
  const unsigned short* vSrc = Vb + vr * 1024 + vc * 8;

  floatx4 oacc[2][4];
#pragma unroll
  for (int t = 0; t < 2; t++)
#pragma unroll
    for (int u = 0; u < 4; u++) oacc[t][u] = (floatx4){0.f, 0.f, 0.f, 0.f};
  float lrun[2][4] = {{0.f, 0.f, 0.f, 0.f}, {0.f, 0.f, 0.f, 0.f}};

  // prologue: stage buffer 0
  async_ld16(kSrc, (char*)&lK[0][0] + wave * 1024);
  async_ld16(vSrc, (char*)&lV[0][0] + wave * 1024);

  const int vca = quad ^ (l16 & 3) ^ ((l16 >> 2) & 3);  // V read swizzle

  for (int ks = 0; ks < 1024; ks += 32) {
    const int buf = (ks >> 5) & 1;
    __syncthreads();  // drains this buffer's staged loads (vmcnt(0) @ barrier)
    const int kn = ks + 32;
    if (kn < 1024) {
      async_ld16(kSrc + kn * 64, (char*)&lK[buf ^ 1][0] + wave * 1024);
      async_ld16(vSrc + kn,      (char*)&lV[buf ^ 1][0] + wave * 1024);
    }
    // K fragments (shared by both Q tiles)
    short8 kf[2][2];
#pragma unroll
    for (int i = 0; i < 2; i++)
#pragma unroll
      for (int h = 0; h < 2; h++) {
        const int gr = (i * 16 + l16) * 8 + ((h * 4 + quad) ^ (l16 & 7));
        kf[i][h] = *(const short8*)(&lK[buf][gr * 8]);
      }
    // QK^T
    floatx4 s[2][2];
#pragma unroll
    for (int t = 0; t < 2; t++)
#pragma unroll
      for (int i = 0; i < 2; i++) {
        const floatx4 z = {0.f, 0.f, 0.f, 0.f};
        floatx4 a = __builtin_amdgcn_mfma_f32_16x16x32_bf16(qf[t][0], kf[i][0], z, 0, 0, 0);
        s[t][i] = __builtin_amdgcn_mfma_f32_16x16x32_bf16(qf[t][1], kf[i][1], a, 0, 0, 0);
      }
    // softmax numerators + P slabs
#pragma unroll
    for (int t = 0; t < 2; t++)
#pragma unroll
      for (int r = 0; r < 4; r++) {
        const float p0 = fast_exp2(s[t][0][r]);
        const float p1 = fast_exp2(s[t][1][r]);
        lrun[t][r] += p0 + p1;
        P[wave][t][quad * 4 + r][l16] = p0;
        P[wave][t][quad * 4 + r][16 + l16] = p1;
      }
    // V fragments (shared by both Q tiles)
    short8 vf[4];
#pragma unroll
    for (int u = 0; u < 4; u++)
      vf[u] = *(const short8*)(&lV[buf][((u * 16 + l16) * 4 + vca) * 8]);
    // P: C-layout -> A-operand layout via private LDS slab (intra-wave)
    short8 pf[2];
#pragma unroll
    for (int t = 0; t < 2; t++) {
      const float* pr = &P[wave][t][l16][quad * 8];
      const floatx4 pa = *(const floatx4*)pr;
      const floatx4 pb = *(const floatx4*)(pr + 4);
      pf[t][0] = (short)f2bf(pa[0]); pf[t][1] = (short)f2bf(pa[1]);
      pf[t][2] = (short)f2bf(pa[2]); pf[t][3] = (short)f2bf(pa[3]);
      pf[t][4] = (short)f2bf(pb[0]); pf[t][5] = (short)f2bf(pb[1]);
      pf[t][6] = (short)f2bf(pb[2]); pf[t][7] = (short)f2bf(pb[3]);
    }
    // P @ V
#pragma unroll
    for (int t = 0; t < 2; t++)
#pragma unroll
      for (int u = 0; u < 4; u++)
        oacc[t][u] = __builtin_amdgcn_mfma_f32_16x16x32_bf16(pf[t], vf[u], oacc[t][u], 0, 0, 0);
  }

  // final denominator reduce across the 16 kv-lanes
  const int b = bh >> 4, h = bh & 15;
#pragma unroll
  for (int t = 0; t < 2; t++) {
#pragma unroll
    for (int r = 0; r < 4; r++) {
      float lr = lrun[t][r];
      lr += __shfl_xor(lr, 1);
      lr += __shfl_xor(lr, 2);
      lr += __shfl_xor(lr, 4);
      lr += __shfl_xor(lr, 8);
      const float linv = 1.0f / lr;
#pragma unroll
      for (int u = 0; u < 4; u++) {
        O[((long)b * 1024 + q0 + t * 16 + quad * 4 + r) * 1024 + h * 64 + u * 16 + l16] =
            f2bf(oacc[t][u][r] * linv);
      }
    }
  }
}

// ---------------------------------------------------------------------------
extern "C" void kernel_launch(void* const* d_in, const int* in_sizes, int n_in,
                              void* d_out, int out_size, void* d_ws, size_t ws_size,
                              hipStream_t stream) {
  const float* x      = (const float*)d_in[0];
  const float* ln1_g  = (const float*)d_in[1];
  const float* ln1_b  = (const float*)d_in[2];
  const float* ln2_g  = (const float*)d_in[3];
  const float* ln2_b  = (const float*)d_in[4];
  const float* qkv_w  = (const float*)d_in[5];
  const float* q_bias = (const float*)d_in[6];
  const float* v_bias = (const float*)d_in[7];
  const float* proj_w = (const float*)d_in[8];
  const float* proj_b = (const float*)d_in[9];
  const float* fc1_w  = (const float*)d_in[10];
  const float* fc1_b  = (const float*)d_in[11];
  const float* fc2_w  = (const float*)d_in[12];
  const float* fc2_b  = (const float*)d_in[13];
  float* out = (float*)d_out;

  char* ws = (char*)d_ws;
  unsigned short* Wqkv  = (unsigned short*)(ws);              //  6 MB
  unsigned short* Wproj = (unsigned short*)(ws + 6291456);    //  2 MB
  unsigned short* Wfc1  = (unsigned short*)(ws + 8388608);    //  8 MB
  unsigned short* Wfc2  = (unsigned short*)(ws + 16777216);   //  8 MB
  float*          X1    = (float*)        (ws + 25165824);    // 32 MB fp32
  unsigned short* Hbuf  = (unsigned short*)(ws + 58720256);   // 16 MB
  unsigned short* Qbuf  = (unsigned short*)(ws + 75497472);   // 16 MB
  unsigned short* Kbuf  = (unsigned short*)(ws + 92274688);   // 16 MB
  unsigned short* Vtbuf = (unsigned short*)(ws + 109051904);  // 16 MB
  unsigned short* Obuf  = (unsigned short*)(ws + 125829120);  // 16 MB
  unsigned short* ACT   = Qbuf;  // reuse dead Q/K/Vt/O region: 64 MB

  // weights -> bf16
  cvt_bf16<<<3072 * 1024 / 1024, 256, 0, stream>>>(qkv_w, Wqkv);
  cvt_bf16<<<1024 * 1024 / 1024, 256, 0, stream>>>(proj_w, Wproj);
  cvt_bf16<<<4096 * 1024 / 1024, 256, 0, stream>>>(fc1_w, Wfc1);
  cvt_bf16<<<4096 * 1024 / 1024, 256, 0, stream>>>(fc2_w, Wfc2);

  // LN1
  ln_bf16<<<8192, 256, 0, stream>>>(x, ln1_g, ln1_b, Hbuf);
  // QKV gemm + scatter (q scaled by 0.125*log2e, v -> transposed)
  gemm_bt<0><<<24 * 64, 256, 0, stream>>>(Hbuf, Wqkv, 8192, 3072, 1024,
                                          q_bias, v_bias, nullptr,
                                          Qbuf, Kbuf, Vtbuf);
  // attention
  attn<<<1024, 256, 0, stream>>>(Qbuf, Kbuf, Vtbuf, Obuf);
  // proj + residual -> X1 (fp32)
  gemm_bt<1><<<8 * 64, 256, 0, stream>>>(Obuf, Wproj, 8192, 1024, 1024,
                                         proj_b, nullptr, x,
                                         X1, nullptr, nullptr);
  // LN2
  ln_bf16<<<8192, 256, 0, stream>>>(X1, ln2_g, ln2_b, Hbuf);
  // fc1 + gelu -> ACT (bf16)
  gemm_bt<2><<<32 * 64, 256, 0, stream>>>(Hbuf, Wfc1, 8192, 4096, 1024,
                                          fc1_b, nullptr, nullptr,
                                          ACT, nullptr, nullptr);
  // fc2 + residual -> out (fp32)
  gemm_bt<1><<<8 * 64, 256, 0, stream>>>(ACT, Wfc2, 8192, 1024, 4096,
                                         fc2_b, nullptr, X1,
                                         out, nullptr, nullptr);
  (void)in_sizes; (void)n_in; (void)out_size; (void)ws_size;
}